// Round 1
// baseline (119.883 us; speedup 1.0000x reference)
//
#include <hip/hip_runtime.h>

// Problem constants (from reference): B=32, N=2048, S=64, D=1024, fp32.
constexpr int B = 32;
constexpr int N = 2048;
constexpr int S = 64;
constexpr int D = 1024;
constexpr int ROW4 = D / 4; // 256 float4 per row

// Pass 1: winner[b*N + n] = max s such that idx[b,s] == n, else -1.
// (memset to 0xFF gives -1; atomicMax over s implements "last duplicate wins",
//  matching numpy sequential s[i]=v semantics.)
__global__ void build_winner(const int* __restrict__ idx,
                             int* __restrict__ winner) {
    int t = blockIdx.x * blockDim.x + threadIdx.x;
    if (t >= B * S) return;
    int b = t / S;
    int s = t - b * S;
    int n = idx[t];
    // n is guaranteed in [0, N) by the reference's randint
    atomicMax(&winner[b * N + n], s);
}

// Pass 2: fused copy + scatter-interpolate.
// out[b,n,:] = (winner<0) ? state[b,n,:]
//                         : (1-p[b,w])*state[b,n,:] + p[b,w]*substate[b,w,:]
__global__ void fused_update(const float4* __restrict__ state,
                             const float4* __restrict__ substate,
                             const float* __restrict__ probs,
                             const int* __restrict__ winner,
                             float4* __restrict__ out) {
    const long total = (long)B * N * ROW4; // 16,777,216 float4 elements
    const long stride = (long)gridDim.x * blockDim.x;
    for (long gid = (long)blockIdx.x * blockDim.x + threadIdx.x; gid < total;
         gid += stride) {
        int row = (int)(gid >> 8);        // gid / ROW4
        int e   = (int)(gid & (ROW4 - 1));
        int w = winner[row];              // broadcast-ish read, L2-hot (256 KB)
        float4 g = state[gid];
        float4 o;
        if (w >= 0) {
            int b  = row >> 11;           // row / N
            int bs = b * S + w;
            float p = probs[bs];
            float q = 1.0f - p;
            float4 v = substate[(long)bs * ROW4 + e];
            o.x = q * g.x + p * v.x;
            o.y = q * g.y + p * v.y;
            o.z = q * g.z + p * v.z;
            o.w = q * g.w + p * v.w;
        } else {
            o = g;
        }
        out[gid] = o;
    }
}

extern "C" void kernel_launch(void* const* d_in, const int* in_sizes, int n_in,
                              void* d_out, int out_size, void* d_ws, size_t ws_size,
                              hipStream_t stream) {
    const float4* state    = (const float4*)d_in[0];
    const float4* substate = (const float4*)d_in[1];
    const int*    idx      = (const int*)d_in[2];
    const float*  probs    = (const float*)d_in[3];
    float4*       out      = (float4*)d_out;
    int*          winner   = (int*)d_ws; // B*N ints = 256 KB

    // winner := -1 everywhere (0xFFFFFFFF == -1)
    hipMemsetAsync(winner, 0xFF, (size_t)B * N * sizeof(int), stream);

    // build winner map: B*S = 2048 threads
    build_winner<<<(B * S + 255) / 256, 256, 0, stream>>>(idx, winner);

    // fused copy/interpolate: memory-bound grid-stride
    const int block = 256;
    const int grid  = 2048; // ~8 blocks/CU on 256 CUs, grid-stride covers rest
    fused_update<<<grid, block, 0, stream>>>(state, substate, probs, winner, out);
}

// Round 2
// 109.395 us; speedup vs baseline: 1.0959x; 1.0959x over previous
//
#include <hip/hip_runtime.h>

// Problem constants (from reference): B=32, N=2048, S=64, D=1024, fp32.
constexpr int B = 32;
constexpr int N = 2048;
constexpr int S = 64;
constexpr int D = 1024;
constexpr int ROW4 = D / 4;                      // 256 float4 per row
constexpr long TOTAL4 = (long)B * N * ROW4;      // 16,777,216 float4
constexpr int GRID  = 2048;                      // 8 blocks/CU on 256 CUs
constexpr int BLOCK = 256;
constexpr int ITERS = (int)(TOTAL4 / ((long)GRID * BLOCK)); // exactly 32

typedef float f4 __attribute__((ext_vector_type(4)));

// Single-dispatch setup: clear winner map, then scatter last-occurrence-wins.
// One block => __syncthreads() is a valid fence between the two phases.
__global__ void setup_winner(const int* __restrict__ idx,
                             int* __restrict__ winner) {
    for (int i = threadIdx.x; i < B * N; i += blockDim.x) winner[i] = -1;
    __syncthreads();
    for (int t = threadIdx.x; t < B * S; t += blockDim.x) {
        int b = t >> 6;          // t / S
        int s = t & (S - 1);     // t % S
        // atomicMax over s == last duplicate wins (numpy .at[i].set semantics)
        atomicMax(&winner[b * N + idx[t]], s);
    }
}

// Fused copy + scatter-interpolate, exact trip count, unrolled for MLP.
// state/out are single-use streams -> nontemporal; winner/probs/substate are
// small hot working sets -> normal cached loads.
__global__ __launch_bounds__(BLOCK) void fused_update(
    const f4* __restrict__ state, const f4* __restrict__ substate,
    const float* __restrict__ probs, const int* __restrict__ winner,
    f4* __restrict__ out) {
    const long stride = (long)GRID * BLOCK;
    const long base = (long)blockIdx.x * BLOCK + threadIdx.x;
#pragma unroll 4
    for (int it = 0; it < ITERS; ++it) {
        long gid = base + (long)it * stride;
        int row = (int)(gid >> 8);           // gid / ROW4
        int e   = (int)(gid & (ROW4 - 1));
        int w = winner[row];                 // wave-uniform, L2-hot (256 KB)
        f4 g = __builtin_nontemporal_load(&state[gid]);
        f4 o;
        if (w >= 0) {
            int b  = row >> 11;              // row / N
            int bs = b * S + w;
            float p = probs[bs];
            f4 v = substate[(long)bs * ROW4 + e];
            o = (1.0f - p) * g + p * v;
        } else {
            o = g;
        }
        __builtin_nontemporal_store(o, &out[gid]);
    }
}

extern "C" void kernel_launch(void* const* d_in, const int* in_sizes, int n_in,
                              void* d_out, int out_size, void* d_ws, size_t ws_size,
                              hipStream_t stream) {
    const f4*    state    = (const f4*)d_in[0];
    const f4*    substate = (const f4*)d_in[1];
    const int*   idx      = (const int*)d_in[2];
    const float* probs    = (const float*)d_in[3];
    f4*          out      = (f4*)d_out;
    int*         winner   = (int*)d_ws;      // B*N ints = 256 KB

    setup_winner<<<1, 1024, 0, stream>>>(idx, winner);
    fused_update<<<GRID, BLOCK, 0, stream>>>(state, substate, probs, winner, out);
}

// Round 3
// 106.738 us; speedup vs baseline: 1.1232x; 1.0249x over previous
//
#include <hip/hip_runtime.h>

// Problem constants (from reference): B=32, N=2048, S=64, D=1024, fp32.
constexpr int B = 32;
constexpr int N = 2048;
constexpr int S = 64;
constexpr int D = 1024;
constexpr int ROW4 = D / 4;                 // 256 float4 per row
constexpr int BLOCK = 256;
constexpr int CHUNKS_PER_BATCH = 64;        // blocks per batch
constexpr int ROWS_PER_CHUNK = N / CHUNKS_PER_BATCH;        // 32 rows
constexpr int F4_PER_CHUNK = ROWS_PER_CHUNK * ROW4;         // 8192
constexpr int ITERS = F4_PER_CHUNK / BLOCK;                 // 32
constexpr int GRID = B * CHUNKS_PER_BATCH;  // 2048 blocks = 8/CU on 256 CUs

typedef float f4 __attribute__((ext_vector_type(4)));

// Single fused kernel. Each block owns 32 consecutive rows of one batch.
// It first builds that batch's winner map in LDS (last-duplicate-wins via
// atomicMax over s+1; 0 = not selected), then streams its chunk:
//   out[b,n,:] = selected ? (1-p)*state[b,n,:] + p*substate[b,w,:]
//                         : state[b,n,:]
__global__ __launch_bounds__(BLOCK) void fused_update(
    const f4* __restrict__ state, const f4* __restrict__ substate,
    const float* __restrict__ probs, const int* __restrict__ idx,
    f4* __restrict__ out) {
    __shared__ int win[N];                  // 8 KB
    const int b = blockIdx.x >> 6;          // batch
    const int chunk = blockIdx.x & 63;

    // build per-batch winner map in LDS (cost amortized over 32 stream iters)
    for (int i = threadIdx.x; i < N; i += BLOCK) win[i] = 0;
    __syncthreads();
    if (threadIdx.x < S)
        atomicMax(&win[idx[b * S + threadIdx.x]], threadIdx.x + 1);
    __syncthreads();

    const long batchBase = (long)b * (N * ROW4);
    const int chunkBase = chunk * F4_PER_CHUNK;
#pragma unroll 4
    for (int it = 0; it < ITERS; ++it) {
        int off = chunkBase + it * BLOCK + threadIdx.x;
        long gid = batchBase + off;
        int row = off >> 8;                 // wave-uniform (64 lanes = 1/4 row)
        int e   = off & (ROW4 - 1);
        int w = win[row];                   // LDS broadcast, no bank conflict
        f4 g = __builtin_nontemporal_load(&state[gid]);
        f4 o = g;
        if (w > 0) {                        // wave-uniform branch
            int bs = (b << 6) + (w - 1);
            float p = probs[bs];            // L2-hot, wave-uniform
            f4 v = substate[(long)bs * ROW4 + e];
            o = (1.0f - p) * g + p * v;
        }
        __builtin_nontemporal_store(o, &out[gid]);
    }
}

extern "C" void kernel_launch(void* const* d_in, const int* in_sizes, int n_in,
                              void* d_out, int out_size, void* d_ws, size_t ws_size,
                              hipStream_t stream) {
    const f4*    state    = (const f4*)d_in[0];
    const f4*    substate = (const f4*)d_in[1];
    const int*   idx      = (const int*)d_in[2];
    const float* probs    = (const float*)d_in[3];
    f4*          out      = (f4*)d_out;

    fused_update<<<GRID, BLOCK, 0, stream>>>(state, substate, probs, idx, out);
}